// Round 16
// baseline (346.495 us; speedup 1.0000x reference)
//
#include <hip/hip_runtime.h>
#include <cstdint>

static constexpr float kEps  = 1e-5f;
static constexpr float kBeta = 0.1f;

typedef __attribute__((ext_vector_type(8))) short bf16x8;
typedef __attribute__((ext_vector_type(4))) float f32x4;
typedef __attribute__((ext_vector_type(2))) float f32x2;

__device__ __forceinline__ ushort f2bf(float f){
  uint u = __float_as_uint(f);
  u += 0x7fff + ((u>>16)&1);      // round-to-nearest-even
  return (ushort)(u>>16);
}
__device__ __forceinline__ float bf2f(ushort h){
  return __uint_as_float(((uint)h)<<16);
}

// ---------------- CSR build (XCD-binned) ----------------
__global__ void k_hist_bin(const int* __restrict__ row, int* __restrict__ deg,
                           int E, int NR){
  const int p  = blockIdx.x & 7;
  const int q  = blockIdx.x >> 3;
  const int NQ = gridDim.x >> 3;
  const int lo = p*NR, hi = lo + NR;
  for (int e = q*256 + threadIdx.x; e < E; e += NQ*256){
    int r = row[e];
    if (r >= lo && r < hi) atomicAdd(&deg[r], 1);
  }
}

__global__ void k_scan_block(const int* __restrict__ deg, int* __restrict__ start,
                             int* __restrict__ bsum, int N){
  __shared__ int s[256];
  int t = threadIdx.x;
  int i = blockIdx.x*256 + t;
  int v = (i < N) ? deg[i] : 0;
  s[t] = v; __syncthreads();
  for (int off=1; off<256; off<<=1){
    int add = (t >= off) ? s[t-off] : 0;
    __syncthreads();
    s[t] += add;
    __syncthreads();
  }
  if (i < N) start[i+1] = s[t];
  if (t == 255) bsum[blockIdx.x] = s[255];
}

__global__ void k_scan_bsum(const int* __restrict__ bsum, int* __restrict__ boff, int nb){
  __shared__ int s[256];
  int t = threadIdx.x;
  int v = (t < nb) ? bsum[t] : 0;
  s[t] = v; __syncthreads();
  for (int off=1; off<256; off<<=1){
    int add = (t >= off) ? s[t-off] : 0;
    __syncthreads();
    s[t] += add;
    __syncthreads();
  }
  if (t < nb) boff[t] = s[t] - v;   // exclusive
}

__global__ void k_scan_add(int* __restrict__ start, const int* __restrict__ boff, int N){
  int i = blockIdx.x*256 + threadIdx.x;
  if (i < N) start[i+1] += boff[blockIdx.x];
  if (blockIdx.x==0 && threadIdx.x==0) start[0] = 0;
}

__global__ void k_fill_bin(const int* __restrict__ row, const int* __restrict__ col,
                           const int* __restrict__ start, int* __restrict__ cursor,
                           int* __restrict__ colcsr, int E, int NR){
  const int p  = blockIdx.x & 7;
  const int q  = blockIdx.x >> 3;
  const int NQ = gridDim.x >> 3;
  const int lo = p*NR, hi = lo + NR;
  for (int e = q*256 + threadIdx.x; e < E; e += NQ*256){
    int r = row[e];
    if (r >= lo && r < hi){
      int pos = atomicAdd(&cursor[r], 1);
      colcsr[start[r] + pos] = col[e];
    }
  }
}

// ---------------- W1 -> bf16, k-chunk-contiguous layout ----------------
__global__ void k_prep_w1(const float* __restrict__ W1, ushort* __restrict__ W1s){
  int i = blockIdx.x*256 + threadIdx.x;   // i = k*256 + col
  int k = i >> 8, col = i & 255;
  W1s[(k>>5)*8192 + col*32 + (k&31)] = f2bf(W1[i]);
}

// ---- [256][64] fp32 weight -> split hi/lo bf16, layout [kc][col][kk] ----
__global__ void k_prep_w64(const float* __restrict__ W,
                           ushort* __restrict__ Wh, ushort* __restrict__ Wl){
  int i = blockIdx.x*256 + threadIdx.x;   // i = k*64 + col, 16384 total
  int k = i >> 6, col = i & 63;
  int dst = (k>>5)*2048 + col*32 + (k&31);
  float w = W[i];
  ushort hb = f2bf(w);
  Wh[dst] = hb;
  Wl[dst] = f2bf(w - bf2f(hb));
}

// ---------------- GEMM1 (MFMA, split-x bf16) + bias + relu + LN -> ego(bf16) ----
__global__ __launch_bounds__(256) void k_gemm1_mfma(const float* __restrict__ x,
    const ushort* __restrict__ W1s, const float* __restrict__ b1,
    const float* __restrict__ g, const float* __restrict__ bb,
    ushort* __restrict__ ego, int N){
  __shared__ ushort xh[64][40];
  __shared__ ushort xl[64][40];
  __shared__ ushort wl[256][40];
  __shared__ float psum[64][4], psq[64][4];
  __shared__ float mub[64], ivb[64];

  const int tid = threadIdx.x;
  const int n0  = blockIdx.x*64;
  const int w   = tid>>6;
  const int l   = tid&63;
  const int l15 = l&15;
  const int lg  = l>>4;            // 0..3
  const int cb  = w*64;            // wave col base
  const int sxr = tid>>2;          // x row 0..63
  const int sxk = (tid&3)*8;       // k offset {0,8,16,24}

  f32x4 acc[4][4];
  #pragma unroll
  for (int rt=0;rt<4;rt++)
    #pragma unroll
    for (int ct=0;ct<4;ct++)
      acc[rt][ct] = (f32x4){0.f,0.f,0.f,0.f};

  for (int kc=0; kc<8; ++kc){
    if (kc) __syncthreads();
    const float* xp = &x[(size_t)min(n0+sxr, N-1)*256 + kc*32 + sxk];
    float4 v0 = *reinterpret_cast<const float4*>(xp);
    float4 v1 = *reinterpret_cast<const float4*>(xp+4);
    const float vv[8] = {v0.x,v0.y,v0.z,v0.w,v1.x,v1.y,v1.z,v1.w};
    bf16x8 hv, lv;
    #pragma unroll
    for (int j=0;j<8;j++){
      ushort hb = f2bf(vv[j]);
      hv[j] = (short)hb;
      lv[j] = (short)f2bf(vv[j] - bf2f(hb));
    }
    *reinterpret_cast<bf16x8*>(&xh[sxr][sxk]) = hv;
    *reinterpret_cast<bf16x8*>(&xl[sxr][sxk]) = lv;
    const ushort* wp = &W1s[kc*8192 + tid*32];
    #pragma unroll
    for (int s=0;s<4;s++)
      *reinterpret_cast<bf16x8*>(&wl[tid][s*8]) =
          *reinterpret_cast<const bf16x8*>(wp + s*8);
    __syncthreads();
    bf16x8 ah[4], al[4];
    #pragma unroll
    for (int rt=0;rt<4;rt++){
      ah[rt] = *reinterpret_cast<const bf16x8*>(&xh[rt*16+l15][lg*8]);
      al[rt] = *reinterpret_cast<const bf16x8*>(&xl[rt*16+l15][lg*8]);
    }
    #pragma unroll
    for (int ct=0;ct<4;ct++){
      bf16x8 bv = *reinterpret_cast<const bf16x8*>(&wl[cb+ct*16+l15][lg*8]);
      #pragma unroll
      for (int rt=0;rt<4;rt++){
        acc[rt][ct] = __builtin_amdgcn_mfma_f32_16x16x32_bf16(al[rt], bv, acc[rt][ct], 0,0,0);
        acc[rt][ct] = __builtin_amdgcn_mfma_f32_16x16x32_bf16(ah[rt], bv, acc[rt][ct], 0,0,0);
      }
    }
  }

  float b1v[4], gv[4], bbv[4];
  #pragma unroll
  for (int ct=0;ct<4;ct++){
    int col = cb + ct*16 + l15;
    b1v[ct] = b1[col]; gv[ct] = g[col]; bbv[ct] = bb[col];
  }
  #pragma unroll
  for (int rt=0;rt<4;rt++)
    #pragma unroll
    for (int ct=0;ct<4;ct++)
      #pragma unroll
      for (int r=0;r<4;r++)
        acc[rt][ct][r] = fmaxf(acc[rt][ct][r] + b1v[ct], 0.f);

  #pragma unroll
  for (int rt=0;rt<4;rt++){
    #pragma unroll
    for (int r=0;r<4;r++){
      float s = acc[rt][0][r]+acc[rt][1][r]+acc[rt][2][r]+acc[rt][3][r];
      float q = acc[rt][0][r]*acc[rt][0][r]+acc[rt][1][r]*acc[rt][1][r]
              + acc[rt][2][r]*acc[rt][2][r]+acc[rt][3][r]*acc[rt][3][r];
      #pragma unroll
      for (int o=1;o<16;o<<=1){ s += __shfl_xor(s,o); q += __shfl_xor(q,o); }
      if (l15 == 0){
        int row = rt*16 + lg*4 + r;
        psum[row][w] = s; psq[row][w] = q;
      }
    }
  }
  __syncthreads();
  if (tid < 64){
    float s = psum[tid][0]+psum[tid][1]+psum[tid][2]+psum[tid][3];
    float q = psq[tid][0]+psq[tid][1]+psq[tid][2]+psq[tid][3];
    float mu  = s * (1.f/256.f);
    float var = q * (1.f/256.f) - mu*mu;
    mub[tid] = mu;
    ivb[tid] = rsqrtf(fmaxf(var, 0.f) + kEps);
  }
  __syncthreads();
  #pragma unroll
  for (int rt=0;rt<4;rt++){
    #pragma unroll
    for (int r=0;r<4;r++){
      int row  = rt*16 + lg*4 + r;
      int grow = n0 + row;
      if (grow < N){
        float mu = mub[row], inv = ivb[row];
        size_t base = (size_t)grow*256 + cb + l15;
        #pragma unroll
        for (int ct=0;ct<4;ct++)
          ego[base + ct*16] = f2bf((acc[rt][ct][r]-mu)*inv*gv[ct] + bbv[ct]);
      }
    }
  }
}

// ------- MFMA 256->64 GEMM (bf16 x, split W) -> bf16 h -------
__global__ __launch_bounds__(256) void k_hgemm_mfma(const ushort* __restrict__ x,
    const ushort* __restrict__ Wh, const ushort* __restrict__ Wl,
    ushort* __restrict__ h, int N){
  __shared__ ushort xs[64][40];
  __shared__ ushort wh[64][40];
  __shared__ ushort wl[64][40];
  const int tid = threadIdx.x;
  const int n0  = blockIdx.x*64;
  const int w   = tid>>6;
  const int l15 = tid&15;
  const int lg  = (tid&63)>>4;
  const int sxr = tid>>2;
  const int sxk = (tid&3)*8;

  f32x4 acc[4];
  #pragma unroll
  for (int ct=0;ct<4;ct++) acc[ct] = (f32x4){0.f,0.f,0.f,0.f};

  for (int kc=0; kc<8; ++kc){
    if (kc) __syncthreads();
    *reinterpret_cast<bf16x8*>(&xs[sxr][sxk]) =
        *reinterpret_cast<const bf16x8*>(&x[(size_t)min(n0+sxr, N-1)*256 + kc*32 + sxk]);
    int src = kc*2048 + sxr*32 + sxk;
    *reinterpret_cast<bf16x8*>(&wh[sxr][sxk]) =
        *reinterpret_cast<const bf16x8*>(&Wh[src]);
    *reinterpret_cast<bf16x8*>(&wl[sxr][sxk]) =
        *reinterpret_cast<const bf16x8*>(&Wl[src]);
    __syncthreads();
    bf16x8 ah = *reinterpret_cast<const bf16x8*>(&xs[w*16+l15][lg*8]);
    #pragma unroll
    for (int ct=0;ct<4;ct++){
      bf16x8 bh = *reinterpret_cast<const bf16x8*>(&wh[ct*16+l15][lg*8]);
      bf16x8 bl = *reinterpret_cast<const bf16x8*>(&wl[ct*16+l15][lg*8]);
      acc[ct] = __builtin_amdgcn_mfma_f32_16x16x32_bf16(ah, bl, acc[ct], 0,0,0);
      acc[ct] = __builtin_amdgcn_mfma_f32_16x16x32_bf16(ah, bh, acc[ct], 0,0,0);
    }
  }
  #pragma unroll
  for (int r=0;r<4;r++){
    int grow = n0 + w*16 + lg*4 + r;
    if (grow < N){
      #pragma unroll
      for (int ct=0;ct<4;ct++)
        h[(size_t)grow*64 + ct*16 + l15] = f2bf(acc[ct][r]);
    }
  }
}

// ------- MFMA 256->64 GEMM + bias + log_softmax -> out -------
__global__ __launch_bounds__(256) void k_out_mfma(const ushort* __restrict__ x,
    const ushort* __restrict__ Wh, const ushort* __restrict__ Wl,
    const float* __restrict__ b2, float* __restrict__ out, int N){
  __shared__ ushort xs[64][40];
  __shared__ ushort wh[64][40];
  __shared__ ushort wl[64][40];
  const int tid = threadIdx.x;
  const int n0  = blockIdx.x*64;
  const int w   = tid>>6;
  const int l15 = tid&15;
  const int lg  = (tid&63)>>4;
  const int sxr = tid>>2;
  const int sxk = (tid&3)*8;

  f32x4 acc[4];
  #pragma unroll
  for (int ct=0;ct<4;ct++) acc[ct] = (f32x4){0.f,0.f,0.f,0.f};

  for (int kc=0; kc<8; ++kc){
    if (kc) __syncthreads();
    *reinterpret_cast<bf16x8*>(&xs[sxr][sxk]) =
        *reinterpret_cast<const bf16x8*>(&x[(size_t)min(n0+sxr, N-1)*256 + kc*32 + sxk]);
    int src = kc*2048 + sxr*32 + sxk;
    *reinterpret_cast<bf16x8*>(&wh[sxr][sxk]) =
        *reinterpret_cast<const bf16x8*>(&Wh[src]);
    *reinterpret_cast<bf16x8*>(&wl[sxr][sxk]) =
        *reinterpret_cast<const bf16x8*>(&Wl[src]);
    __syncthreads();
    bf16x8 ah = *reinterpret_cast<const bf16x8*>(&xs[w*16+l15][lg*8]);
    #pragma unroll
    for (int ct=0;ct<4;ct++){
      bf16x8 bh = *reinterpret_cast<const bf16x8*>(&wh[ct*16+l15][lg*8]);
      bf16x8 bl = *reinterpret_cast<const bf16x8*>(&wl[ct*16+l15][lg*8]);
      acc[ct] = __builtin_amdgcn_mfma_f32_16x16x32_bf16(ah, bl, acc[ct], 0,0,0);
      acc[ct] = __builtin_amdgcn_mfma_f32_16x16x32_bf16(ah, bh, acc[ct], 0,0,0);
    }
  }

  float b2v[4];
  #pragma unroll
  for (int ct=0;ct<4;ct++) b2v[ct] = b2[ct*16+l15];

  #pragma unroll
  for (int r=0;r<4;r++){
    float v[4];
    #pragma unroll
    for (int ct=0;ct<4;ct++) v[ct] = acc[ct][r] + b2v[ct];
    float mx = fmaxf(fmaxf(v[0],v[1]), fmaxf(v[2],v[3]));
    #pragma unroll
    for (int o=1;o<16;o<<=1) mx = fmaxf(mx, __shfl_xor(mx,o));
    float sm = __expf(v[0]-mx)+__expf(v[1]-mx)+__expf(v[2]-mx)+__expf(v[3]-mx);
    #pragma unroll
    for (int o=1;o<16;o<<=1) sm += __shfl_xor(sm,o);
    float ls = __logf(sm);
    int grow = n0 + w*16 + lg*4 + r;
    if (grow < N){
      #pragma unroll
      for (int ct=0;ct<4;ct++)
        out[(size_t)grow*64 + ct*16 + l15] = (v[ct]-mx) - ls;
    }
  }
}

// ------- FUSED edge attention + aggregate + relu + LN + residual -------
// Wave per node; 4 groups x 16 lanes; group g walks slots g, g+4, ...
// h[row] loaded ONCE per node; per edge only h[col] is gathered (1 row-gather
// per edge vs 3 in the split version). Logits via in-group butterfly
// (shfl_xor o<16 never crosses the 16-lane group -> exec-safe under
// group-divergent loop bounds). Softmax fp32 in-register.
__global__ __launch_bounds__(256) void k_att_agg(
    const ushort* __restrict__ h,      // [N][64] bf16
    const int* __restrict__ colcsr, const int* __restrict__ start,
    const float* __restrict__ attw,    // [64][4]
    const ushort* __restrict__ ego,    // [N][256] bf16
    const float* __restrict__ g, const float* __restrict__ b,
    ushort* __restrict__ xout, int N){
  __shared__ int s_col[4][64];
  const int lane = threadIdx.x & 63;
  const int wid  = threadIdx.x >> 6;
  const int grp  = lane >> 4;
  const int l15  = lane & 15;
  const int n = blockIdx.x*4 + wid;
  if (n >= N) return;

  const int s0 = start[n], s1 = start[n+1];
  const int deg = s1 - s0;
  const int dcap = min(deg, 64);
  const size_t hoff = (size_t)l15*4;

  // per-lane attention weight rows for dims l15*4..+3
  float4 aw0 = *reinterpret_cast<const float4*>(&attw[(l15*4+0)*4]);
  float4 aw1 = *reinterpret_cast<const float4*>(&attw[(l15*4+1)*4]);
  float4 aw2 = *reinterpret_cast<const float4*>(&attw[(l15*4+2)*4]);
  float4 aw3 = *reinterpret_cast<const float4*>(&attw[(l15*4+3)*4]);

  // 0.5 * h[row] for this lane's dims (loaded once per node)
  float hr0, hr1, hr2, hr3;
  {
    ushort4 hv = *reinterpret_cast<const ushort4*>(&h[(size_t)n*64 + hoff]);
    hr0 = 0.5f*bf2f(hv.x); hr1 = 0.5f*bf2f(hv.y);
    hr2 = 0.5f*bf2f(hv.z); hr3 = 0.5f*bf2f(hv.w);
  }

  // stage cols in wave-private LDS (same-wave write->read, no barrier)
  if (lane < dcap) s_col[wid][lane] = colcsr[s0 + lane];

  f32x2 acc2[4][2];
  #pragma unroll
  for (int c=0;c<4;c++){ acc2[c][0]=(f32x2){0.f,0.f}; acc2[c][1]=(f32x2){0.f,0.f}; }

  auto edge_proc = [&](ushort4 hv){
    float hc0=bf2f(hv.x), hc1=bf2f(hv.y), hc2=bf2f(hv.z), hc3=bf2f(hv.w);
    float p0 = fmaxf(hr0 + hc0, 0.f);
    float p1 = fmaxf(hr1 + hc1, 0.f);
    float p2 = fmaxf(hr2 + hc2, 0.f);
    float p3 = fmaxf(hr3 + hc3, 0.f);
    float q0 = p0*aw0.x + p1*aw1.x + p2*aw2.x + p3*aw3.x;
    float q1 = p0*aw0.y + p1*aw1.y + p2*aw2.y + p3*aw3.y;
    float q2 = p0*aw0.z + p1*aw1.z + p2*aw2.z + p3*aw3.z;
    float q3 = p0*aw0.w + p1*aw1.w + p2*aw2.w + p3*aw3.w;
    #pragma unroll
    for (int o=1;o<16;o<<=1){
      q0 += __shfl_xor(q0,o); q1 += __shfl_xor(q1,o);
      q2 += __shfl_xor(q2,o); q3 += __shfl_xor(q3,o);
    }
    float m = fmaxf(fmaxf(q0,q1), fmaxf(q2,q3));
    float e0=__expf(q0-m), e1=__expf(q1-m), e2=__expf(q2-m), e3=__expf(q3-m);
    float inv = 1.f/(e0+e1+e2+e3);
    float a0=e0*inv, a1=e1*inv, a2=e2*inv, a3=e3*inv;
    f32x2 hlo = (f32x2){hc0,hc1};
    f32x2 hhi = (f32x2){hc2,hc3};
    acc2[0][0] += (f32x2){a0,a0}*hlo; acc2[0][1] += (f32x2){a0,a0}*hhi;
    acc2[1][0] += (f32x2){a1,a1}*hlo; acc2[1][1] += (f32x2){a1,a1}*hhi;
    acc2[2][0] += (f32x2){a2,a2}*hlo; acc2[2][1] += (f32x2){a2,a2}*hhi;
    acc2[3][0] += (f32x2){a3,a3}*hlo; acc2[3][1] += (f32x2){a3,a3}*hhi;
  };

  // 4-wide: batch the 4 gathers, then process (shuffle chains interleave)
  int t = grp;
  for (; t + 12 < dcap; t += 16){
    int c0 = s_col[wid][t],   c1 = s_col[wid][t+4];
    int c2 = s_col[wid][t+8], c3 = s_col[wid][t+12];
    ushort4 v0 = *reinterpret_cast<const ushort4*>(&h[(size_t)c0*64 + hoff]);
    ushort4 v1 = *reinterpret_cast<const ushort4*>(&h[(size_t)c1*64 + hoff]);
    ushort4 v2 = *reinterpret_cast<const ushort4*>(&h[(size_t)c2*64 + hoff]);
    ushort4 v3 = *reinterpret_cast<const ushort4*>(&h[(size_t)c3*64 + hoff]);
    edge_proc(v0); edge_proc(v1); edge_proc(v2); edge_proc(v3);
  }
  for (; t < dcap; t += 4){
    int cn = s_col[wid][t];
    edge_proc(*reinterpret_cast<const ushort4*>(&h[(size_t)cn*64 + hoff]));
  }
  // rare deg>64 tail: direct colcsr loads (group-convergent)
  for (int i = s0 + 64 + grp; i < s1; i += 4){
    int cn = colcsr[i];
    edge_proc(*reinterpret_cast<const ushort4*>(&h[(size_t)cn*64 + hoff]));
  }

  float acc[4][4];
  #pragma unroll
  for (int c=0;c<4;c++){
    acc[c][0]=acc2[c][0].x; acc[c][1]=acc2[c][0].y;
    acc[c][2]=acc2[c][1].x; acc[c][3]=acc2[c][1].y;
  }

  // combine the 4 groups, relu
  #pragma unroll
  for (int c=0;c<4;c++)
    #pragma unroll
    for (int j=0;j<4;j++){
      float v = acc[c][j];
      v += __shfl_xor(v,16);
      v += __shfl_xor(v,32);
      acc[c][j] = fmaxf(v, 0.f);
    }

  float s=0.f, sq=0.f;
  #pragma unroll
  for (int c=0;c<4;c++)
    #pragma unroll
    for (int j=0;j<4;j++){ float v=acc[c][j]; s+=v; sq+=v*v; }
  #pragma unroll
  for (int o=1;o<16;o<<=1){ s += __shfl_xor(s,o); sq += __shfl_xor(sq,o); }
  float mu  = s * (1.f/256.f);
  float var = sq * (1.f/256.f) - mu*mu;
  float inv = rsqrtf(fmaxf(var,0.f) + kEps);

  int colb = grp*64 + l15*4;
  float4 gv  = *reinterpret_cast<const float4*>(&g[colb]);
  float4 bv  = *reinterpret_cast<const float4*>(&b[colb]);
  size_t base = (size_t)n*256 + colb;
  ushort4 ev = *reinterpret_cast<const ushort4*>(&ego[base]);
  ushort4 y;
  y.x = f2bf((1.f-kBeta)*((acc[grp][0]-mu)*inv*gv.x + bv.x) + kBeta*bf2f(ev.x));
  y.y = f2bf((1.f-kBeta)*((acc[grp][1]-mu)*inv*gv.y + bv.y) + kBeta*bf2f(ev.y));
  y.z = f2bf((1.f-kBeta)*((acc[grp][2]-mu)*inv*gv.z + bv.z) + kBeta*bf2f(ev.z));
  y.w = f2bf((1.f-kBeta)*((acc[grp][3]-mu)*inv*gv.w + bv.w) + kBeta*bf2f(ev.w));
  *reinterpret_cast<ushort4*>(&xout[base]) = y;
}

extern "C" void kernel_launch(void* const* d_in, const int* in_sizes, int n_in,
                              void* d_out, int out_size, void* d_ws, size_t ws_size,
                              hipStream_t stream){
  const float* x_in = (const float*)d_in[0];
  const int*   ei   = (const int*)d_in[1];
  const float* W1   = (const float*)d_in[2];
  const float* b1   = (const float*)d_in[3];
  const float* lin  = (const float*)d_in[4];
  const float* att  = (const float*)d_in[5];
  const float* lng  = (const float*)d_in[6];
  const float* lnb  = (const float*)d_in[7];
  const float* W2   = (const float*)d_in[8];
  const float* b2   = (const float*)d_in[9];
  float* out = (float*)d_out;

  const int N = in_sizes[0] / 256;   // 50000
  const int E = in_sizes[1] / 2;     // 800000
  const int* row = ei;
  const int* col = ei + E;

  char* basep = (char*)d_ws;
  size_t off = 0;
  auto alloc = [&](size_t bytes)->char*{
    char* p = basep + off;
    off += (bytes + 255) & ~(size_t)255;
    return p;
  };
  ushort* ego    = (ushort*)alloc((size_t)N*256*2);
  ushort* xbuf   = (ushort*)alloc((size_t)N*256*2);
  ushort* hbuf   = (ushort*)alloc((size_t)N*64*2);
  int*    startp = (int*)   alloc((size_t)(N+1)*4);
  int*    deg    = (int*)   alloc((size_t)N*4);   // also reused as cursor
  int*    colcsr = (int*)   alloc((size_t)E*4);
  int*    bsum   = (int*)   alloc(256*4);
  int*    boff   = (int*)   alloc(256*4);
  ushort* W1s    = (ushort*)alloc((size_t)256*256*2);
  ushort* linh   = (ushort*)alloc((size_t)2*16384*2);
  ushort* linl   = (ushort*)alloc((size_t)2*16384*2);
  ushort* W2h    = (ushort*)alloc((size_t)16384*2);
  ushort* W2l    = (ushort*)alloc((size_t)16384*2);

  int nbN = (N + 255)/256;   // 196
  int nbT = (N + 63)/64;     // 782 tiles
  int NR  = (N + 7)/8;       // node range per XCD class

  // CSR build (binned hist + fill)
  hipMemsetAsync(deg, 0, (size_t)N*4, stream);
  k_hist_bin<<<1024,256,0,stream>>>(row, deg, E, NR);
  k_scan_block<<<nbN,256,0,stream>>>(deg, startp, bsum, N);
  k_scan_bsum<<<1,256,0,stream>>>(bsum, boff, nbN);
  k_scan_add<<<nbN,256,0,stream>>>(startp, boff, N);
  hipMemsetAsync(deg, 0, (size_t)N*4, stream);     // cursor
  k_fill_bin<<<1024,256,0,stream>>>(row, col, startp, deg, colcsr, E, NR);

  // weight prep
  k_prep_w1<<<256,256,0,stream>>>(W1, W1s);
  k_prep_w64<<<64,256,0,stream>>>(lin,          linh,          linl);
  k_prep_w64<<<64,256,0,stream>>>(lin + 16384,  linh + 16384,  linl + 16384);
  k_prep_w64<<<64,256,0,stream>>>(W2, W2h, W2l);

  // MFMA projection + bias + relu + LN -> ego (bf16)
  k_gemm1_mfma<<<nbT,256,0,stream>>>(x_in, W1s, b1, lng, lnb, ego, N);

  for (int L=0; L<2; ++L){
    const ushort* xsrc = (L == 0) ? ego : xbuf;
    k_hgemm_mfma<<<nbT,256,0,stream>>>(xsrc, linh + (size_t)L*16384,
                                       linl + (size_t)L*16384, hbuf, N);
    k_att_agg<<<(N+3)/4,256,0,stream>>>(hbuf, colcsr, startp,
                                        att + (size_t)L*64*4, ego,
                                        lng + (size_t)(L+1)*256, lnb + (size_t)(L+1)*256,
                                        xbuf, N);
  }
  k_out_mfma<<<nbT,256,0,stream>>>(xbuf, W2h, W2l, b2, out, N);
}

// Round 17
// 300.583 us; speedup vs baseline: 1.1527x; 1.1527x over previous
//
#include <hip/hip_runtime.h>
#include <cstdint>

static constexpr float kEps  = 1e-5f;
static constexpr float kBeta = 0.1f;

typedef __attribute__((ext_vector_type(8))) short bf16x8;
typedef __attribute__((ext_vector_type(4))) float f32x4;
typedef __attribute__((ext_vector_type(2))) float f32x2;
typedef __attribute__((ext_vector_type(4))) _Float16 f16x4;

__device__ __forceinline__ ushort f2bf(float f){
  uint u = __float_as_uint(f);
  u += 0x7fff + ((u>>16)&1);      // round-to-nearest-even
  return (ushort)(u>>16);
}
__device__ __forceinline__ float bf2f(ushort h){
  return __uint_as_float(((uint)h)<<16);
}

// ---------------- CSR build (XCD-binned) ----------------
__global__ void k_hist_bin(const int* __restrict__ row, int* __restrict__ deg,
                           int E, int NR){
  const int p  = blockIdx.x & 7;
  const int q  = blockIdx.x >> 3;
  const int NQ = gridDim.x >> 3;
  const int lo = p*NR, hi = lo + NR;
  for (int e = q*256 + threadIdx.x; e < E; e += NQ*256){
    int r = row[e];
    if (r >= lo && r < hi) atomicAdd(&deg[r], 1);
  }
}

__global__ void k_scan_block(const int* __restrict__ deg, int* __restrict__ start,
                             int* __restrict__ bsum, int N){
  __shared__ int s[256];
  int t = threadIdx.x;
  int i = blockIdx.x*256 + t;
  int v = (i < N) ? deg[i] : 0;
  s[t] = v; __syncthreads();
  for (int off=1; off<256; off<<=1){
    int add = (t >= off) ? s[t-off] : 0;
    __syncthreads();
    s[t] += add;
    __syncthreads();
  }
  if (i < N) start[i+1] = s[t];
  if (t == 255) bsum[blockIdx.x] = s[255];
}

__global__ void k_scan_bsum(const int* __restrict__ bsum, int* __restrict__ boff, int nb){
  __shared__ int s[256];
  int t = threadIdx.x;
  int v = (t < nb) ? bsum[t] : 0;
  s[t] = v; __syncthreads();
  for (int off=1; off<256; off<<=1){
    int add = (t >= off) ? s[t-off] : 0;
    __syncthreads();
    s[t] += add;
    __syncthreads();
  }
  if (t < nb) boff[t] = s[t] - v;   // exclusive
}

__global__ void k_scan_add(int* __restrict__ start, const int* __restrict__ boff, int N){
  int i = blockIdx.x*256 + threadIdx.x;
  if (i < N) start[i+1] += boff[blockIdx.x];
  if (blockIdx.x==0 && threadIdx.x==0) start[0] = 0;
}

__global__ void k_fill_bin(const int* __restrict__ row, const int* __restrict__ col,
                           const int* __restrict__ start, int* __restrict__ cursor,
                           int* __restrict__ colcsr, int E, int NR){
  const int p  = blockIdx.x & 7;
  const int q  = blockIdx.x >> 3;
  const int NQ = gridDim.x >> 3;
  const int lo = p*NR, hi = lo + NR;
  for (int e = q*256 + threadIdx.x; e < E; e += NQ*256){
    int r = row[e];
    if (r >= lo && r < hi){
      int pos = atomicAdd(&cursor[r], 1);
      colcsr[start[r] + pos] = col[e];
    }
  }
}

__global__ void k_rowfill(const int* __restrict__ start, int* __restrict__ rowcsr, int N){
  int n = blockIdx.x*256 + threadIdx.x;
  if (n < N){
    int s0 = start[n], s1 = start[n+1];
    for (int i=s0; i<s1; ++i) rowcsr[i] = n;
  }
}

// ---------------- W1 -> bf16, k-chunk-contiguous layout ----------------
__global__ void k_prep_w1(const float* __restrict__ W1, ushort* __restrict__ W1s){
  int i = blockIdx.x*256 + threadIdx.x;   // i = k*256 + col
  int k = i >> 8, col = i & 255;
  W1s[(k>>5)*8192 + col*32 + (k&31)] = f2bf(W1[i]);
}

// ---- [256][64] fp32 weight -> split hi/lo bf16, layout [kc][col][kk] ----
__global__ void k_prep_w64(const float* __restrict__ W,
                           ushort* __restrict__ Wh, ushort* __restrict__ Wl){
  int i = blockIdx.x*256 + threadIdx.x;   // i = k*64 + col, 16384 total
  int k = i >> 6, col = i & 63;
  int dst = (k>>5)*2048 + col*32 + (k&31);
  float w = W[i];
  ushort hb = f2bf(w);
  Wh[dst] = hb;
  Wl[dst] = f2bf(w - bf2f(hb));
}

// ---------------- GEMM1 (MFMA, split-x bf16) + bias + relu + LN -> ego(bf16) ----
__global__ __launch_bounds__(256) void k_gemm1_mfma(const float* __restrict__ x,
    const ushort* __restrict__ W1s, const float* __restrict__ b1,
    const float* __restrict__ g, const float* __restrict__ bb,
    ushort* __restrict__ ego, int N){
  __shared__ ushort xh[64][40];
  __shared__ ushort xl[64][40];
  __shared__ ushort wl[256][40];
  __shared__ float psum[64][4], psq[64][4];
  __shared__ float mub[64], ivb[64];

  const int tid = threadIdx.x;
  const int n0  = blockIdx.x*64;
  const int w   = tid>>6;
  const int l   = tid&63;
  const int l15 = l&15;
  const int lg  = l>>4;            // 0..3
  const int cb  = w*64;            // wave col base
  const int sxr = tid>>2;          // x row 0..63
  const int sxk = (tid&3)*8;       // k offset {0,8,16,24}

  f32x4 acc[4][4];
  #pragma unroll
  for (int rt=0;rt<4;rt++)
    #pragma unroll
    for (int ct=0;ct<4;ct++)
      acc[rt][ct] = (f32x4){0.f,0.f,0.f,0.f};

  for (int kc=0; kc<8; ++kc){
    if (kc) __syncthreads();
    const float* xp = &x[(size_t)min(n0+sxr, N-1)*256 + kc*32 + sxk];
    float4 v0 = *reinterpret_cast<const float4*>(xp);
    float4 v1 = *reinterpret_cast<const float4*>(xp+4);
    const float vv[8] = {v0.x,v0.y,v0.z,v0.w,v1.x,v1.y,v1.z,v1.w};
    bf16x8 hv, lv;
    #pragma unroll
    for (int j=0;j<8;j++){
      ushort hb = f2bf(vv[j]);
      hv[j] = (short)hb;
      lv[j] = (short)f2bf(vv[j] - bf2f(hb));
    }
    *reinterpret_cast<bf16x8*>(&xh[sxr][sxk]) = hv;
    *reinterpret_cast<bf16x8*>(&xl[sxr][sxk]) = lv;
    const ushort* wp = &W1s[kc*8192 + tid*32];
    #pragma unroll
    for (int s=0;s<4;s++)
      *reinterpret_cast<bf16x8*>(&wl[tid][s*8]) =
          *reinterpret_cast<const bf16x8*>(wp + s*8);
    __syncthreads();
    bf16x8 ah[4], al[4];
    #pragma unroll
    for (int rt=0;rt<4;rt++){
      ah[rt] = *reinterpret_cast<const bf16x8*>(&xh[rt*16+l15][lg*8]);
      al[rt] = *reinterpret_cast<const bf16x8*>(&xl[rt*16+l15][lg*8]);
    }
    #pragma unroll
    for (int ct=0;ct<4;ct++){
      bf16x8 bv = *reinterpret_cast<const bf16x8*>(&wl[cb+ct*16+l15][lg*8]);
      #pragma unroll
      for (int rt=0;rt<4;rt++){
        acc[rt][ct] = __builtin_amdgcn_mfma_f32_16x16x32_bf16(al[rt], bv, acc[rt][ct], 0,0,0);
        acc[rt][ct] = __builtin_amdgcn_mfma_f32_16x16x32_bf16(ah[rt], bv, acc[rt][ct], 0,0,0);
      }
    }
  }

  float b1v[4], gv[4], bbv[4];
  #pragma unroll
  for (int ct=0;ct<4;ct++){
    int col = cb + ct*16 + l15;
    b1v[ct] = b1[col]; gv[ct] = g[col]; bbv[ct] = bb[col];
  }
  #pragma unroll
  for (int rt=0;rt<4;rt++)
    #pragma unroll
    for (int ct=0;ct<4;ct++)
      #pragma unroll
      for (int r=0;r<4;r++)
        acc[rt][ct][r] = fmaxf(acc[rt][ct][r] + b1v[ct], 0.f);

  #pragma unroll
  for (int rt=0;rt<4;rt++){
    #pragma unroll
    for (int r=0;r<4;r++){
      float s = acc[rt][0][r]+acc[rt][1][r]+acc[rt][2][r]+acc[rt][3][r];
      float q = acc[rt][0][r]*acc[rt][0][r]+acc[rt][1][r]*acc[rt][1][r]
              + acc[rt][2][r]*acc[rt][2][r]+acc[rt][3][r]*acc[rt][3][r];
      #pragma unroll
      for (int o=1;o<16;o<<=1){ s += __shfl_xor(s,o); q += __shfl_xor(q,o); }
      if (l15 == 0){
        int row = rt*16 + lg*4 + r;
        psum[row][w] = s; psq[row][w] = q;
      }
    }
  }
  __syncthreads();
  if (tid < 64){
    float s = psum[tid][0]+psum[tid][1]+psum[tid][2]+psum[tid][3];
    float q = psq[tid][0]+psq[tid][1]+psq[tid][2]+psq[tid][3];
    float mu  = s * (1.f/256.f);
    float var = q * (1.f/256.f) - mu*mu;
    mub[tid] = mu;
    ivb[tid] = rsqrtf(fmaxf(var, 0.f) + kEps);
  }
  __syncthreads();
  #pragma unroll
  for (int rt=0;rt<4;rt++){
    #pragma unroll
    for (int r=0;r<4;r++){
      int row  = rt*16 + lg*4 + r;
      int grow = n0 + row;
      if (grow < N){
        float mu = mub[row], inv = ivb[row];
        size_t base = (size_t)grow*256 + cb + l15;
        #pragma unroll
        for (int ct=0;ct<4;ct++)
          ego[base + ct*16] = f2bf((acc[rt][ct][r]-mu)*inv*gv[ct] + bbv[ct]);
      }
    }
  }
}

// ------- MFMA 256->64 GEMM (bf16 x, split W) -> bf16 h -------
__global__ __launch_bounds__(256) void k_hgemm_mfma(const ushort* __restrict__ x,
    const ushort* __restrict__ Wh, const ushort* __restrict__ Wl,
    ushort* __restrict__ h, int N){
  __shared__ ushort xs[64][40];
  __shared__ ushort wh[64][40];
  __shared__ ushort wl[64][40];
  const int tid = threadIdx.x;
  const int n0  = blockIdx.x*64;
  const int w   = tid>>6;
  const int l15 = tid&15;
  const int lg  = (tid&63)>>4;
  const int sxr = tid>>2;
  const int sxk = (tid&3)*8;

  f32x4 acc[4];
  #pragma unroll
  for (int ct=0;ct<4;ct++) acc[ct] = (f32x4){0.f,0.f,0.f,0.f};

  for (int kc=0; kc<8; ++kc){
    if (kc) __syncthreads();
    *reinterpret_cast<bf16x8*>(&xs[sxr][sxk]) =
        *reinterpret_cast<const bf16x8*>(&x[(size_t)min(n0+sxr, N-1)*256 + kc*32 + sxk]);
    int src = kc*2048 + sxr*32 + sxk;
    *reinterpret_cast<bf16x8*>(&wh[sxr][sxk]) =
        *reinterpret_cast<const bf16x8*>(&Wh[src]);
    *reinterpret_cast<bf16x8*>(&wl[sxr][sxk]) =
        *reinterpret_cast<const bf16x8*>(&Wl[src]);
    __syncthreads();
    bf16x8 ah = *reinterpret_cast<const bf16x8*>(&xs[w*16+l15][lg*8]);
    #pragma unroll
    for (int ct=0;ct<4;ct++){
      bf16x8 bh = *reinterpret_cast<const bf16x8*>(&wh[ct*16+l15][lg*8]);
      bf16x8 bl = *reinterpret_cast<const bf16x8*>(&wl[ct*16+l15][lg*8]);
      acc[ct] = __builtin_amdgcn_mfma_f32_16x16x32_bf16(ah, bl, acc[ct], 0,0,0);
      acc[ct] = __builtin_amdgcn_mfma_f32_16x16x32_bf16(ah, bh, acc[ct], 0,0,0);
    }
  }
  #pragma unroll
  for (int r=0;r<4;r++){
    int grow = n0 + w*16 + lg*4 + r;
    if (grow < N){
      #pragma unroll
      for (int ct=0;ct<4;ct++)
        h[(size_t)grow*64 + ct*16 + l15] = f2bf(acc[ct][r]);
    }
  }
}

// ------- MFMA 256->64 GEMM + bias + log_softmax -> out -------
__global__ __launch_bounds__(256) void k_out_mfma(const ushort* __restrict__ x,
    const ushort* __restrict__ Wh, const ushort* __restrict__ Wl,
    const float* __restrict__ b2, float* __restrict__ out, int N){
  __shared__ ushort xs[64][40];
  __shared__ ushort wh[64][40];
  __shared__ ushort wl[64][40];
  const int tid = threadIdx.x;
  const int n0  = blockIdx.x*64;
  const int w   = tid>>6;
  const int l15 = tid&15;
  const int lg  = (tid&63)>>4;
  const int sxr = tid>>2;
  const int sxk = (tid&3)*8;

  f32x4 acc[4];
  #pragma unroll
  for (int ct=0;ct<4;ct++) acc[ct] = (f32x4){0.f,0.f,0.f,0.f};

  for (int kc=0; kc<8; ++kc){
    if (kc) __syncthreads();
    *reinterpret_cast<bf16x8*>(&xs[sxr][sxk]) =
        *reinterpret_cast<const bf16x8*>(&x[(size_t)min(n0+sxr, N-1)*256 + kc*32 + sxk]);
    int src = kc*2048 + sxr*32 + sxk;
    *reinterpret_cast<bf16x8*>(&wh[sxr][sxk]) =
        *reinterpret_cast<const bf16x8*>(&Wh[src]);
    *reinterpret_cast<bf16x8*>(&wl[sxr][sxk]) =
        *reinterpret_cast<const bf16x8*>(&Wl[src]);
    __syncthreads();
    bf16x8 ah = *reinterpret_cast<const bf16x8*>(&xs[w*16+l15][lg*8]);
    #pragma unroll
    for (int ct=0;ct<4;ct++){
      bf16x8 bh = *reinterpret_cast<const bf16x8*>(&wh[ct*16+l15][lg*8]);
      bf16x8 bl = *reinterpret_cast<const bf16x8*>(&wl[ct*16+l15][lg*8]);
      acc[ct] = __builtin_amdgcn_mfma_f32_16x16x32_bf16(ah, bl, acc[ct], 0,0,0);
      acc[ct] = __builtin_amdgcn_mfma_f32_16x16x32_bf16(ah, bh, acc[ct], 0,0,0);
    }
  }

  float b2v[4];
  #pragma unroll
  for (int ct=0;ct<4;ct++) b2v[ct] = b2[ct*16+l15];

  #pragma unroll
  for (int r=0;r<4;r++){
    float v[4];
    #pragma unroll
    for (int ct=0;ct<4;ct++) v[ct] = acc[ct][r] + b2v[ct];
    float mx = fmaxf(fmaxf(v[0],v[1]), fmaxf(v[2],v[3]));
    #pragma unroll
    for (int o=1;o<16;o<<=1) mx = fmaxf(mx, __shfl_xor(mx,o));
    float sm = __expf(v[0]-mx)+__expf(v[1]-mx)+__expf(v[2]-mx)+__expf(v[3]-mx);
    #pragma unroll
    for (int o=1;o<16;o<<=1) sm += __shfl_xor(sm,o);
    float ls = __logf(sm);
    int grow = n0 + w*16 + lg*4 + r;
    if (grow < N){
      #pragma unroll
      for (int ct=0;ct<4;ct++)
        out[(size_t)grow*64 + ct*16 + l15] = (v[ct]-mx) - ls;
    }
  }
}

// ---------------- edge attention, lane = edge (CSR order), fp16 out ----------------
__global__ __launch_bounds__(256) void k_edge(
    const ushort* __restrict__ h,
    const int* __restrict__ rowcsr, const int* __restrict__ colcsr,
    const float* __restrict__ attw,    // [64][4]
    f16x4* __restrict__ a_csr, int E){
  int e = blockIdx.x*256 + threadIdx.x;
  if (e >= E) return;
  int r = rowcsr[e], c = colcsr[e];
  const uint4* hrp = reinterpret_cast<const uint4*>(h + (size_t)r*64);
  const uint4* hcp = reinterpret_cast<const uint4*>(h + (size_t)c*64);

  float q0=0.f, q1=0.f, q2=0.f, q3=0.f;
  #pragma unroll
  for (int s=0; s<8; ++s){
    uint4 hr4 = hrp[s];
    uint4 hc4 = hcp[s];
    const uint hru[4] = {hr4.x, hr4.y, hr4.z, hr4.w};
    const uint hcu[4] = {hc4.x, hc4.y, hc4.z, hc4.w};
    #pragma unroll
    for (int t=0; t<4; ++t){
      float hrl = __uint_as_float(hru[t]<<16);
      float hrh = __uint_as_float(hru[t]&0xffff0000u);
      float hcl = __uint_as_float(hcu[t]<<16);
      float hch = __uint_as_float(hcu[t]&0xffff0000u);
      float pl = fmaxf(fmaf(0.5f, hrl, hcl), 0.f);
      float ph = fmaxf(fmaf(0.5f, hrh, hch), 0.f);
      int d = s*8 + t*2;
      float4 w0 = *reinterpret_cast<const float4*>(&attw[(d  )*4]);  // uniform
      float4 w1 = *reinterpret_cast<const float4*>(&attw[(d+1)*4]);  // uniform
      q0 = fmaf(pl, w0.x, q0); q1 = fmaf(pl, w0.y, q1);
      q2 = fmaf(pl, w0.z, q2); q3 = fmaf(pl, w0.w, q3);
      q0 = fmaf(ph, w1.x, q0); q1 = fmaf(ph, w1.y, q1);
      q2 = fmaf(ph, w1.z, q2); q3 = fmaf(ph, w1.w, q3);
    }
  }
  float m = fmaxf(fmaxf(q0,q1), fmaxf(q2,q3));
  float e0=__expf(q0-m), e1=__expf(q1-m), e2=__expf(q2-m), e3=__expf(q3-m);
  float inv = 1.f/(e0+e1+e2+e3);
  f16x4 av;
  av[0] = (_Float16)(e0*inv); av[1] = (_Float16)(e1*inv);
  av[2] = (_Float16)(e2*inv); av[3] = (_Float16)(e3*inv);
  a_csr[e] = av;
}

// ------- aggregate + relu + LN + residual (4/2/1-wide ILP inner loop) -------
__global__ __launch_bounds__(256) void k_agg(
    const ushort* __restrict__ h,      // [N][64] bf16
    const int* __restrict__ colcsr, const int* __restrict__ start,
    const f16x4* __restrict__ a_csr,
    const ushort* __restrict__ ego,    // [N][256] bf16
    const float* __restrict__ g, const float* __restrict__ b,
    ushort* __restrict__ xout, int N){
  const int lane = threadIdx.x & 63;
  const int grp  = lane >> 4;
  const int l15  = lane & 15;
  const int n = blockIdx.x*4 + (threadIdx.x >> 6);
  if (n >= N) return;

  float acc[4][4];   // [gate][dim j]
  #pragma unroll
  for (int c=0;c<4;c++)
    #pragma unroll
    for (int j=0;j<4;j++) acc[c][j]=0.f;

  const int s0 = start[n], s1 = start[n+1];
  const size_t hoff = (size_t)l15*4;

  auto edge_acc = [&](float a0, float a1, float a2, float a3, ushort4 hv){
    float d0=bf2f(hv.x), d1=bf2f(hv.y), d2=bf2f(hv.z), d3=bf2f(hv.w);
    acc[0][0]=fmaf(a0,d0,acc[0][0]); acc[0][1]=fmaf(a0,d1,acc[0][1]);
    acc[0][2]=fmaf(a0,d2,acc[0][2]); acc[0][3]=fmaf(a0,d3,acc[0][3]);
    acc[1][0]=fmaf(a1,d0,acc[1][0]); acc[1][1]=fmaf(a1,d1,acc[1][1]);
    acc[1][2]=fmaf(a1,d2,acc[1][2]); acc[1][3]=fmaf(a1,d3,acc[1][3]);
    acc[2][0]=fmaf(a2,d0,acc[2][0]); acc[2][1]=fmaf(a2,d1,acc[2][1]);
    acc[2][2]=fmaf(a2,d2,acc[2][2]); acc[2][3]=fmaf(a2,d3,acc[2][3]);
    acc[3][0]=fmaf(a3,d0,acc[3][0]); acc[3][1]=fmaf(a3,d1,acc[3][1]);
    acc[3][2]=fmaf(a3,d2,acc[3][2]); acc[3][3]=fmaf(a3,d3,acc[3][3]);
  };

  int i = s0 + grp;
  // 4-wide
  for (; i + 12 < s1; i += 16){
    int c0 = colcsr[i], c1 = colcsr[i+4], c2 = colcsr[i+8], c3 = colcsr[i+12];
    f16x4 af0 = a_csr[i],   af1 = a_csr[i+4],
          af2 = a_csr[i+8], af3 = a_csr[i+12];
    ushort4 h0 = *reinterpret_cast<const ushort4*>(&h[(size_t)c0*64 + hoff]);
    ushort4 h1 = *reinterpret_cast<const ushort4*>(&h[(size_t)c1*64 + hoff]);
    ushort4 h2 = *reinterpret_cast<const ushort4*>(&h[(size_t)c2*64 + hoff]);
    ushort4 h3 = *reinterpret_cast<const ushort4*>(&h[(size_t)c3*64 + hoff]);
    edge_acc((float)af0[0],(float)af0[1],(float)af0[2],(float)af0[3], h0);
    edge_acc((float)af1[0],(float)af1[1],(float)af1[2],(float)af1[3], h1);
    edge_acc((float)af2[0],(float)af2[1],(float)af2[2],(float)af2[3], h2);
    edge_acc((float)af3[0],(float)af3[1],(float)af3[2],(float)af3[3], h3);
  }
  // 2-wide
  for (; i + 4 < s1; i += 8){
    int c0 = colcsr[i], c1 = colcsr[i+4];
    f16x4 af0 = a_csr[i], af1 = a_csr[i+4];
    ushort4 h0 = *reinterpret_cast<const ushort4*>(&h[(size_t)c0*64 + hoff]);
    ushort4 h1 = *reinterpret_cast<const ushort4*>(&h[(size_t)c1*64 + hoff]);
    edge_acc((float)af0[0],(float)af0[1],(float)af0[2],(float)af0[3], h0);
    edge_acc((float)af1[0],(float)af1[1],(float)af1[2],(float)af1[3], h1);
  }
  // 1-wide tail
  for (; i < s1; i += 4){
    int cn = colcsr[i];
    f16x4 af = a_csr[i];
    ushort4 hv = *reinterpret_cast<const ushort4*>(&h[(size_t)cn*64 + hoff]);
    edge_acc((float)af[0],(float)af[1],(float)af[2],(float)af[3], hv);
  }

  #pragma unroll
  for (int c=0;c<4;c++)
    #pragma unroll
    for (int j=0;j<4;j++){
      float v = acc[c][j];
      v += __shfl_xor(v,16);
      v += __shfl_xor(v,32);
      acc[c][j] = fmaxf(v, 0.f);   // relu
    }

  float s=0.f, sq=0.f;
  #pragma unroll
  for (int c=0;c<4;c++)
    #pragma unroll
    for (int j=0;j<4;j++){ float v=acc[c][j]; s+=v; sq+=v*v; }
  #pragma unroll
  for (int o=1;o<16;o<<=1){ s += __shfl_xor(s,o); sq += __shfl_xor(sq,o); }
  float mu  = s * (1.f/256.f);
  float var = sq * (1.f/256.f) - mu*mu;
  float inv = rsqrtf(fmaxf(var,0.f) + kEps);

  int colb = grp*64 + l15*4;
  float4 gv  = *reinterpret_cast<const float4*>(&g[colb]);
  float4 bv  = *reinterpret_cast<const float4*>(&b[colb]);
  size_t base = (size_t)n*256 + colb;
  ushort4 ev = *reinterpret_cast<const ushort4*>(&ego[base]);
  ushort4 y;
  y.x = f2bf((1.f-kBeta)*((acc[grp][0]-mu)*inv*gv.x + bv.x) + kBeta*bf2f(ev.x));
  y.y = f2bf((1.f-kBeta)*((acc[grp][1]-mu)*inv*gv.y + bv.y) + kBeta*bf2f(ev.y));
  y.z = f2bf((1.f-kBeta)*((acc[grp][2]-mu)*inv*gv.z + bv.z) + kBeta*bf2f(ev.z));
  y.w = f2bf((1.f-kBeta)*((acc[grp][3]-mu)*inv*gv.w + bv.w) + kBeta*bf2f(ev.w));
  *reinterpret_cast<ushort4*>(&xout[base]) = y;
}

extern "C" void kernel_launch(void* const* d_in, const int* in_sizes, int n_in,
                              void* d_out, int out_size, void* d_ws, size_t ws_size,
                              hipStream_t stream){
  const float* x_in = (const float*)d_in[0];
  const int*   ei   = (const int*)d_in[1];
  const float* W1   = (const float*)d_in[2];
  const float* b1   = (const float*)d_in[3];
  const float* lin  = (const float*)d_in[4];
  const float* att  = (const float*)d_in[5];
  const float* lng  = (const float*)d_in[6];
  const float* lnb  = (const float*)d_in[7];
  const float* W2   = (const float*)d_in[8];
  const float* b2   = (const float*)d_in[9];
  float* out = (float*)d_out;

  const int N = in_sizes[0] / 256;   // 50000
  const int E = in_sizes[1] / 2;     // 800000
  const int* row = ei;
  const int* col = ei + E;

  char* basep = (char*)d_ws;
  size_t off = 0;
  auto alloc = [&](size_t bytes)->char*{
    char* p = basep + off;
    off += (bytes + 255) & ~(size_t)255;
    return p;
  };
  ushort* ego    = (ushort*)alloc((size_t)N*256*2);
  ushort* xbuf   = (ushort*)alloc((size_t)N*256*2);
  ushort* hbuf   = (ushort*)alloc((size_t)N*64*2);
  f16x4*  acsr   = (f16x4*) alloc((size_t)E*8);
  int*    startp = (int*)   alloc((size_t)(N+1)*4);
  int*    deg    = (int*)   alloc((size_t)N*4);   // also reused as cursor
  int*    rowcsr = (int*)   alloc((size_t)E*4);
  int*    colcsr = (int*)   alloc((size_t)E*4);
  int*    bsum   = (int*)   alloc(256*4);
  int*    boff   = (int*)   alloc(256*4);
  ushort* W1s    = (ushort*)alloc((size_t)256*256*2);
  ushort* linh   = (ushort*)alloc((size_t)2*16384*2);
  ushort* linl   = (ushort*)alloc((size_t)2*16384*2);
  ushort* W2h    = (ushort*)alloc((size_t)16384*2);
  ushort* W2l    = (ushort*)alloc((size_t)16384*2);

  int nbE = (E + 255)/256;   // 3125
  int nbN = (N + 255)/256;   // 196
  int nbT = (N + 63)/64;     // 782 tiles
  int NR  = (N + 7)/8;       // node range per XCD class

  // CSR build (binned hist + fill)
  hipMemsetAsync(deg, 0, (size_t)N*4, stream);
  k_hist_bin<<<1024,256,0,stream>>>(row, deg, E, NR);
  k_scan_block<<<nbN,256,0,stream>>>(deg, startp, bsum, N);
  k_scan_bsum<<<1,256,0,stream>>>(bsum, boff, nbN);
  k_scan_add<<<nbN,256,0,stream>>>(startp, boff, N);
  hipMemsetAsync(deg, 0, (size_t)N*4, stream);     // cursor
  k_fill_bin<<<1024,256,0,stream>>>(row, col, startp, deg, colcsr, E, NR);
  k_rowfill<<<nbN,256,0,stream>>>(startp, rowcsr, N);

  // weight prep
  k_prep_w1<<<256,256,0,stream>>>(W1, W1s);
  k_prep_w64<<<64,256,0,stream>>>(lin,          linh,          linl);
  k_prep_w64<<<64,256,0,stream>>>(lin + 16384,  linh + 16384,  linl + 16384);
  k_prep_w64<<<64,256,0,stream>>>(W2, W2h, W2l);

  // MFMA projection + bias + relu + LN -> ego (bf16)
  k_gemm1_mfma<<<nbT,256,0,stream>>>(x_in, W1s, b1, lng, lnb, ego, N);

  for (int L=0; L<2; ++L){
    const ushort* xsrc = (L == 0) ? ego : xbuf;
    k_hgemm_mfma<<<nbT,256,0,stream>>>(xsrc, linh + (size_t)L*16384,
                                       linl + (size_t)L*16384, hbuf, N);
    k_edge<<<nbE,256,0,stream>>>(hbuf, rowcsr, colcsr,
                                 att + (size_t)L*64*4, acsr, E);
    k_agg<<<(N+3)/4,256,0,stream>>>(hbuf, colcsr, startp, acsr, ego,
                                    lng + (size_t)(L+1)*256, lnb + (size_t)(L+1)*256,
                                    xbuf, N);
  }
  k_out_mfma<<<nbT,256,0,stream>>>(xbuf, W2h, W2l, b2, out, N);
}

// Round 18
// 292.657 us; speedup vs baseline: 1.1840x; 1.0271x over previous
//
#include <hip/hip_runtime.h>
#include <cstdint>

static constexpr float kEps  = 1e-5f;
static constexpr float kBeta = 0.1f;
static constexpr int   kCap  = 128;   // edges buffered per chunk

typedef __attribute__((ext_vector_type(8))) short bf16x8;
typedef __attribute__((ext_vector_type(4))) float f32x4;

__device__ __forceinline__ ushort f2bf(float f){
  uint u = __float_as_uint(f);
  u += 0x7fff + ((u>>16)&1);      // round-to-nearest-even
  return (ushort)(u>>16);
}
__device__ __forceinline__ float bf2f(ushort h){
  return __uint_as_float(((uint)h)<<16);
}

// ---------------- CSR build (XCD-binned) ----------------
__global__ void k_hist_bin(const int* __restrict__ row, int* __restrict__ deg,
                           int E, int NR){
  const int p  = blockIdx.x & 7;
  const int q  = blockIdx.x >> 3;
  const int NQ = gridDim.x >> 3;
  const int lo = p*NR, hi = lo + NR;
  for (int e = q*256 + threadIdx.x; e < E; e += NQ*256){
    int r = row[e];
    if (r >= lo && r < hi) atomicAdd(&deg[r], 1);
  }
}

__global__ void k_scan_block(const int* __restrict__ deg, int* __restrict__ start,
                             int* __restrict__ bsum, int N){
  __shared__ int s[256];
  int t = threadIdx.x;
  int i = blockIdx.x*256 + t;
  int v = (i < N) ? deg[i] : 0;
  s[t] = v; __syncthreads();
  for (int off=1; off<256; off<<=1){
    int add = (t >= off) ? s[t-off] : 0;
    __syncthreads();
    s[t] += add;
    __syncthreads();
  }
  if (i < N) start[i+1] = s[t];
  if (t == 255) bsum[blockIdx.x] = s[255];
}

__global__ void k_scan_bsum(const int* __restrict__ bsum, int* __restrict__ boff, int nb){
  __shared__ int s[256];
  int t = threadIdx.x;
  int v = (t < nb) ? bsum[t] : 0;
  s[t] = v; __syncthreads();
  for (int off=1; off<256; off<<=1){
    int add = (t >= off) ? s[t-off] : 0;
    __syncthreads();
    s[t] += add;
    __syncthreads();
  }
  if (t < nb) boff[t] = s[t] - v;   // exclusive
}

__global__ void k_scan_add(int* __restrict__ start, const int* __restrict__ boff, int N){
  int i = blockIdx.x*256 + threadIdx.x;
  if (i < N) start[i+1] += boff[blockIdx.x];
  if (blockIdx.x==0 && threadIdx.x==0) start[0] = 0;
}

__global__ void k_fill_bin(const int* __restrict__ row, const int* __restrict__ col,
                           const int* __restrict__ start, int* __restrict__ cursor,
                           int* __restrict__ colcsr, int E, int NR){
  const int p  = blockIdx.x & 7;
  const int q  = blockIdx.x >> 3;
  const int NQ = gridDim.x >> 3;
  const int lo = p*NR, hi = lo + NR;
  for (int e = q*256 + threadIdx.x; e < E; e += NQ*256){
    int r = row[e];
    if (r >= lo && r < hi){
      int pos = atomicAdd(&cursor[r], 1);
      colcsr[start[r] + pos] = col[e];
    }
  }
}

__global__ void k_rowfill(const int* __restrict__ start, int* __restrict__ rowcsr, int N){
  int n = blockIdx.x*256 + threadIdx.x;
  if (n < N){
    int s0 = start[n], s1 = start[n+1];
    for (int i=s0; i<s1; ++i) rowcsr[i] = n;
  }
}

// ---------------- W1 -> bf16, k-chunk-contiguous layout ----------------
__global__ void k_prep_w1(const float* __restrict__ W1, ushort* __restrict__ W1s){
  int i = blockIdx.x*256 + threadIdx.x;   // i = k*256 + col
  int k = i >> 8, col = i & 255;
  W1s[(k>>5)*8192 + col*32 + (k&31)] = f2bf(W1[i]);
}

// ---- [256][64] fp32 weight -> split hi/lo bf16, layout [kc][col][kk] ----
__global__ void k_prep_w64(const float* __restrict__ W,
                           ushort* __restrict__ Wh, ushort* __restrict__ Wl){
  int i = blockIdx.x*256 + threadIdx.x;   // i = k*64 + col, 16384 total
  int k = i >> 6, col = i & 63;
  int dst = (k>>5)*2048 + col*32 + (k&31);
  float w = W[i];
  ushort hb = f2bf(w);
  Wh[dst] = hb;
  Wl[dst] = f2bf(w - bf2f(hb));
}

// ---------------- GEMM1 (MFMA, split-x bf16) + bias + relu + LN -> ego(bf16) ----
__global__ __launch_bounds__(256) void k_gemm1_mfma(const float* __restrict__ x,
    const ushort* __restrict__ W1s, const float* __restrict__ b1,
    const float* __restrict__ g, const float* __restrict__ bb,
    ushort* __restrict__ ego, int N){
  __shared__ ushort xh[64][40];
  __shared__ ushort xl[64][40];
  __shared__ ushort wl[256][40];
  __shared__ float psum[64][4], psq[64][4];
  __shared__ float mub[64], ivb[64];

  const int tid = threadIdx.x;
  const int n0  = blockIdx.x*64;
  const int w   = tid>>6;
  const int l   = tid&63;
  const int l15 = l&15;
  const int lg  = l>>4;            // 0..3
  const int cb  = w*64;            // wave col base
  const int sxr = tid>>2;          // x row 0..63
  const int sxk = (tid&3)*8;       // k offset {0,8,16,24}

  f32x4 acc[4][4];
  #pragma unroll
  for (int rt=0;rt<4;rt++)
    #pragma unroll
    for (int ct=0;ct<4;ct++)
      acc[rt][ct] = (f32x4){0.f,0.f,0.f,0.f};

  for (int kc=0; kc<8; ++kc){
    if (kc) __syncthreads();
    const float* xp = &x[(size_t)min(n0+sxr, N-1)*256 + kc*32 + sxk];
    float4 v0 = *reinterpret_cast<const float4*>(xp);
    float4 v1 = *reinterpret_cast<const float4*>(xp+4);
    const float vv[8] = {v0.x,v0.y,v0.z,v0.w,v1.x,v1.y,v1.z,v1.w};
    bf16x8 hv, lv;
    #pragma unroll
    for (int j=0;j<8;j++){
      ushort hb = f2bf(vv[j]);
      hv[j] = (short)hb;
      lv[j] = (short)f2bf(vv[j] - bf2f(hb));
    }
    *reinterpret_cast<bf16x8*>(&xh[sxr][sxk]) = hv;
    *reinterpret_cast<bf16x8*>(&xl[sxr][sxk]) = lv;
    // W staging: 4 lanes per row (bank-conflict-free vs 8-way before)
    #pragma unroll
    for (int s2=0;s2<4;s2++){
      int rowi = (tid>>2) + s2*64;
      *reinterpret_cast<bf16x8*>(&wl[rowi][(tid&3)*8]) =
          *reinterpret_cast<const bf16x8*>(&W1s[kc*8192 + rowi*32 + (tid&3)*8]);
    }
    __syncthreads();
    bf16x8 ah[4], al[4];
    #pragma unroll
    for (int rt=0;rt<4;rt++){
      ah[rt] = *reinterpret_cast<const bf16x8*>(&xh[rt*16+l15][lg*8]);
      al[rt] = *reinterpret_cast<const bf16x8*>(&xl[rt*16+l15][lg*8]);
    }
    #pragma unroll
    for (int ct=0;ct<4;ct++){
      bf16x8 bv = *reinterpret_cast<const bf16x8*>(&wl[cb+ct*16+l15][lg*8]);
      #pragma unroll
      for (int rt=0;rt<4;rt++){
        acc[rt][ct] = __builtin_amdgcn_mfma_f32_16x16x32_bf16(al[rt], bv, acc[rt][ct], 0,0,0);
        acc[rt][ct] = __builtin_amdgcn_mfma_f32_16x16x32_bf16(ah[rt], bv, acc[rt][ct], 0,0,0);
      }
    }
  }

  float b1v[4], gv[4], bbv[4];
  #pragma unroll
  for (int ct=0;ct<4;ct++){
    int col = cb + ct*16 + l15;
    b1v[ct] = b1[col]; gv[ct] = g[col]; bbv[ct] = bb[col];
  }
  #pragma unroll
  for (int rt=0;rt<4;rt++)
    #pragma unroll
    for (int ct=0;ct<4;ct++)
      #pragma unroll
      for (int r=0;r<4;r++)
        acc[rt][ct][r] = fmaxf(acc[rt][ct][r] + b1v[ct], 0.f);

  #pragma unroll
  for (int rt=0;rt<4;rt++){
    #pragma unroll
    for (int r=0;r<4;r++){
      float s = acc[rt][0][r]+acc[rt][1][r]+acc[rt][2][r]+acc[rt][3][r];
      float q = acc[rt][0][r]*acc[rt][0][r]+acc[rt][1][r]*acc[rt][1][r]
              + acc[rt][2][r]*acc[rt][2][r]+acc[rt][3][r]*acc[rt][3][r];
      #pragma unroll
      for (int o=1;o<16;o<<=1){ s += __shfl_xor(s,o); q += __shfl_xor(q,o); }
      if (l15 == 0){
        int row = rt*16 + lg*4 + r;
        psum[row][w] = s; psq[row][w] = q;
      }
    }
  }
  __syncthreads();
  if (tid < 64){
    float s = psum[tid][0]+psum[tid][1]+psum[tid][2]+psum[tid][3];
    float q = psq[tid][0]+psq[tid][1]+psq[tid][2]+psq[tid][3];
    float mu  = s * (1.f/256.f);
    float var = q * (1.f/256.f) - mu*mu;
    mub[tid] = mu;
    ivb[tid] = rsqrtf(fmaxf(var, 0.f) + kEps);
  }
  __syncthreads();
  #pragma unroll
  for (int rt=0;rt<4;rt++){
    #pragma unroll
    for (int r=0;r<4;r++){
      int row  = rt*16 + lg*4 + r;
      int grow = n0 + row;
      if (grow < N){
        float mu = mub[row], inv = ivb[row];
        size_t base = (size_t)grow*256 + cb + l15;
        #pragma unroll
        for (int ct=0;ct<4;ct++)
          ego[base + ct*16] = f2bf((acc[rt][ct][r]-mu)*inv*gv[ct] + bbv[ct]);
      }
    }
  }
}

// ------- MFMA 256->64 GEMM (bf16 x, split W) -> bf16 h -------
__global__ __launch_bounds__(256) void k_hgemm_mfma(const ushort* __restrict__ x,
    const ushort* __restrict__ Wh, const ushort* __restrict__ Wl,
    ushort* __restrict__ h, int N){
  __shared__ ushort xs[64][40];
  __shared__ ushort wh[64][40];
  __shared__ ushort wl[64][40];
  const int tid = threadIdx.x;
  const int n0  = blockIdx.x*64;
  const int w   = tid>>6;
  const int l15 = tid&15;
  const int lg  = (tid&63)>>4;
  const int sxr = tid>>2;
  const int sxk = (tid&3)*8;

  f32x4 acc[4];
  #pragma unroll
  for (int ct=0;ct<4;ct++) acc[ct] = (f32x4){0.f,0.f,0.f,0.f};

  for (int kc=0; kc<8; ++kc){
    if (kc) __syncthreads();
    *reinterpret_cast<bf16x8*>(&xs[sxr][sxk]) =
        *reinterpret_cast<const bf16x8*>(&x[(size_t)min(n0+sxr, N-1)*256 + kc*32 + sxk]);
    int src = kc*2048 + sxr*32 + sxk;
    *reinterpret_cast<bf16x8*>(&wh[sxr][sxk]) =
        *reinterpret_cast<const bf16x8*>(&Wh[src]);
    *reinterpret_cast<bf16x8*>(&wl[sxr][sxk]) =
        *reinterpret_cast<const bf16x8*>(&Wl[src]);
    __syncthreads();
    bf16x8 ah = *reinterpret_cast<const bf16x8*>(&xs[w*16+l15][lg*8]);
    #pragma unroll
    for (int ct=0;ct<4;ct++){
      bf16x8 bh = *reinterpret_cast<const bf16x8*>(&wh[ct*16+l15][lg*8]);
      bf16x8 bl = *reinterpret_cast<const bf16x8*>(&wl[ct*16+l15][lg*8]);
      acc[ct] = __builtin_amdgcn_mfma_f32_16x16x32_bf16(ah, bl, acc[ct], 0,0,0);
      acc[ct] = __builtin_amdgcn_mfma_f32_16x16x32_bf16(ah, bh, acc[ct], 0,0,0);
    }
  }
  #pragma unroll
  for (int r=0;r<4;r++){
    int grow = n0 + w*16 + lg*4 + r;
    if (grow < N){
      #pragma unroll
      for (int ct=0;ct<4;ct++)
        h[(size_t)grow*64 + ct*16 + l15] = f2bf(acc[ct][r]);
    }
  }
}

// ------- MFMA 256->64 GEMM + bias + log_softmax -> out -------
__global__ __launch_bounds__(256) void k_out_mfma(const ushort* __restrict__ x,
    const ushort* __restrict__ Wh, const ushort* __restrict__ Wl,
    const float* __restrict__ b2, float* __restrict__ out, int N){
  __shared__ ushort xs[64][40];
  __shared__ ushort wh[64][40];
  __shared__ ushort wl[64][40];
  const int tid = threadIdx.x;
  const int n0  = blockIdx.x*64;
  const int w   = tid>>6;
  const int l15 = tid&15;
  const int lg  = (tid&63)>>4;
  const int sxr = tid>>2;
  const int sxk = (tid&3)*8;

  f32x4 acc[4];
  #pragma unroll
  for (int ct=0;ct<4;ct++) acc[ct] = (f32x4){0.f,0.f,0.f,0.f};

  for (int kc=0; kc<8; ++kc){
    if (kc) __syncthreads();
    *reinterpret_cast<bf16x8*>(&xs[sxr][sxk]) =
        *reinterpret_cast<const bf16x8*>(&x[(size_t)min(n0+sxr, N-1)*256 + kc*32 + sxk]);
    int src = kc*2048 + sxr*32 + sxk;
    *reinterpret_cast<bf16x8*>(&wh[sxr][sxk]) =
        *reinterpret_cast<const bf16x8*>(&Wh[src]);
    *reinterpret_cast<bf16x8*>(&wl[sxr][sxk]) =
        *reinterpret_cast<const bf16x8*>(&Wl[src]);
    __syncthreads();
    bf16x8 ah = *reinterpret_cast<const bf16x8*>(&xs[w*16+l15][lg*8]);
    #pragma unroll
    for (int ct=0;ct<4;ct++){
      bf16x8 bh = *reinterpret_cast<const bf16x8*>(&wh[ct*16+l15][lg*8]);
      bf16x8 bl = *reinterpret_cast<const bf16x8*>(&wl[ct*16+l15][lg*8]);
      acc[ct] = __builtin_amdgcn_mfma_f32_16x16x32_bf16(ah, bl, acc[ct], 0,0,0);
      acc[ct] = __builtin_amdgcn_mfma_f32_16x16x32_bf16(ah, bh, acc[ct], 0,0,0);
    }
  }

  float b2v[4];
  #pragma unroll
  for (int ct=0;ct<4;ct++) b2v[ct] = b2[ct*16+l15];

  #pragma unroll
  for (int r=0;r<4;r++){
    float v[4];
    #pragma unroll
    for (int ct=0;ct<4;ct++) v[ct] = acc[ct][r] + b2v[ct];
    float mx = fmaxf(fmaxf(v[0],v[1]), fmaxf(v[2],v[3]));
    #pragma unroll
    for (int o=1;o<16;o<<=1) mx = fmaxf(mx, __shfl_xor(mx,o));
    float sm = __expf(v[0]-mx)+__expf(v[1]-mx)+__expf(v[2]-mx)+__expf(v[3]-mx);
    #pragma unroll
    for (int o=1;o<16;o<<=1) sm += __shfl_xor(sm,o);
    float ls = __logf(sm);
    int grow = n0 + w*16 + lg*4 + r;
    if (grow < N){
      #pragma unroll
      for (int ct=0;ct<4;ct++)
        out[(size_t)grow*64 + ct*16 + l15] = (v[ct]-mx) - ls;
    }
  }
}

// ------- FUSED edge phase: attention (lane=edge) -> LDS -> aggregate -------
// Block = 4 nodes. Chunked over the block's edges (CAP=128).
// Phase 1: thread=edge, gather h[row] (L1-hot) + h[col], attention fully
//          in-register (no shuffles), stash a (fp32) + h[col] row in LDS.
// Phase 2: wave=node, accumulate from LDS only. Epilogue = relu+LN+blend.
__global__ __launch_bounds__(256) void k_att_agg(
    const ushort* __restrict__ h,      // [N][64] bf16
    const int* __restrict__ rowcsr, const int* __restrict__ colcsr,
    const int* __restrict__ start,
    const float* __restrict__ attw,    // [64][4]
    const ushort* __restrict__ ego,    // [N][256] bf16
    const float* __restrict__ g, const float* __restrict__ b,
    ushort* __restrict__ xout, int N){
  __shared__ ushort s_hc[kCap][72];    // 144B rows: 16B-aligned, reads conflict-free
  __shared__ float4 s_a[kCap];

  const int tid  = threadIdx.x;
  const int lane = tid & 63;
  const int wid  = tid >> 6;
  const int grp  = lane >> 4;
  const int l15  = lane & 15;
  const int nb   = blockIdx.x*4;
  const int n    = nb + wid;

  const int b0 = start[nb];
  const int b1 = start[min(nb+4, N)];
  const int s0 = (n < N) ? start[n]   : b1;
  const int s1 = (n < N) ? start[n+1] : b1;
  const size_t hoff = (size_t)l15*4;

  float acc[4][4];
  #pragma unroll
  for (int c=0;c<4;c++)
    #pragma unroll
    for (int j=0;j<4;j++) acc[c][j]=0.f;

  for (int base = b0; base < b1; base += kCap){
    const int cnt = min(b1 - base, kCap);
    // ---- phase 1: one thread per edge ----
    for (int e = tid; e < cnt; e += 256){
      int edge = base + e;
      int r = rowcsr[edge], c = colcsr[edge];
      const uint4* hrp = reinterpret_cast<const uint4*>(h + (size_t)r*64);
      const uint4* hcp = reinterpret_cast<const uint4*>(h + (size_t)c*64);
      float q0=0.f, q1=0.f, q2=0.f, q3=0.f;
      #pragma unroll
      for (int s=0; s<8; ++s){
        uint4 hr4 = hrp[s];
        uint4 hc4 = hcp[s];
        *reinterpret_cast<uint4*>(&s_hc[e][s*8]) = hc4;   // stash h[col]
        const uint hru[4] = {hr4.x, hr4.y, hr4.z, hr4.w};
        const uint hcu[4] = {hc4.x, hc4.y, hc4.z, hc4.w};
        #pragma unroll
        for (int t=0; t<4; ++t){
          float hrl = __uint_as_float(hru[t]<<16);
          float hrh = __uint_as_float(hru[t]&0xffff0000u);
          float hcl = __uint_as_float(hcu[t]<<16);
          float hch = __uint_as_float(hcu[t]&0xffff0000u);
          float pl = fmaxf(fmaf(0.5f, hrl, hcl), 0.f);
          float ph = fmaxf(fmaf(0.5f, hrh, hch), 0.f);
          int d = s*8 + t*2;
          float4 w0 = *reinterpret_cast<const float4*>(&attw[(d  )*4]);  // uniform
          float4 w1 = *reinterpret_cast<const float4*>(&attw[(d+1)*4]);  // uniform
          q0 = fmaf(pl, w0.x, q0); q1 = fmaf(pl, w0.y, q1);
          q2 = fmaf(pl, w0.z, q2); q3 = fmaf(pl, w0.w, q3);
          q0 = fmaf(ph, w1.x, q0); q1 = fmaf(ph, w1.y, q1);
          q2 = fmaf(ph, w1.z, q2); q3 = fmaf(ph, w1.w, q3);
        }
      }
      float m = fmaxf(fmaxf(q0,q1), fmaxf(q2,q3));
      float e0=__expf(q0-m), e1=__expf(q1-m), e2=__expf(q2-m), e3=__expf(q3-m);
      float inv = 1.f/(e0+e1+e2+e3);
      s_a[e] = make_float4(e0*inv, e1*inv, e2*inv, e3*inv);
    }
    __syncthreads();
    // ---- phase 2: wave = node, accumulate from LDS ----
    int lo = max(s0, base), hi = min(s1, base + cnt);
    for (int i = lo + grp; i < hi; i += 4){
      int e = i - base;
      float4 av = s_a[e];
      ushort4 hv = *reinterpret_cast<const ushort4*>(&s_hc[e][l15*4]);
      float d0=bf2f(hv.x), d1=bf2f(hv.y), d2=bf2f(hv.z), d3=bf2f(hv.w);
      acc[0][0]=fmaf(av.x,d0,acc[0][0]); acc[0][1]=fmaf(av.x,d1,acc[0][1]);
      acc[0][2]=fmaf(av.x,d2,acc[0][2]); acc[0][3]=fmaf(av.x,d3,acc[0][3]);
      acc[1][0]=fmaf(av.y,d0,acc[1][0]); acc[1][1]=fmaf(av.y,d1,acc[1][1]);
      acc[1][2]=fmaf(av.y,d2,acc[1][2]); acc[1][3]=fmaf(av.y,d3,acc[1][3]);
      acc[2][0]=fmaf(av.z,d0,acc[2][0]); acc[2][1]=fmaf(av.z,d1,acc[2][1]);
      acc[2][2]=fmaf(av.z,d2,acc[2][2]); acc[2][3]=fmaf(av.z,d3,acc[2][3]);
      acc[3][0]=fmaf(av.w,d0,acc[3][0]); acc[3][1]=fmaf(av.w,d1,acc[3][1]);
      acc[3][2]=fmaf(av.w,d2,acc[3][2]); acc[3][3]=fmaf(av.w,d3,acc[3][3]);
    }
    __syncthreads();
  }

  if (n >= N) return;

  // combine the 4 groups, relu
  #pragma unroll
  for (int c=0;c<4;c++)
    #pragma unroll
    for (int j=0;j<4;j++){
      float v = acc[c][j];
      v += __shfl_xor(v,16);
      v += __shfl_xor(v,32);
      acc[c][j] = fmaxf(v, 0.f);
    }

  float s=0.f, sq=0.f;
  #pragma unroll
  for (int c=0;c<4;c++)
    #pragma unroll
    for (int j=0;j<4;j++){ float v=acc[c][j]; s+=v; sq+=v*v; }
  #pragma unroll
  for (int o=1;o<16;o<<=1){ s += __shfl_xor(s,o); sq += __shfl_xor(sq,o); }
  float mu  = s * (1.f/256.f);
  float var = sq * (1.f/256.f) - mu*mu;
  float inv = rsqrtf(fmaxf(var,0.f) + kEps);

  int colb = grp*64 + l15*4;
  float4 gv  = *reinterpret_cast<const float4*>(&g[colb]);
  float4 bv  = *reinterpret_cast<const float4*>(&b[colb]);
  size_t base2 = (size_t)n*256 + colb;
  ushort4 ev = *reinterpret_cast<const ushort4*>(&ego[base2]);
  ushort4 y;
  y.x = f2bf((1.f-kBeta)*((acc[grp][0]-mu)*inv*gv.x + bv.x) + kBeta*bf2f(ev.x));
  y.y = f2bf((1.f-kBeta)*((acc[grp][1]-mu)*inv*gv.y + bv.y) + kBeta*bf2f(ev.y));
  y.z = f2bf((1.f-kBeta)*((acc[grp][2]-mu)*inv*gv.z + bv.z) + kBeta*bf2f(ev.z));
  y.w = f2bf((1.f-kBeta)*((acc[grp][3]-mu)*inv*gv.w + bv.w) + kBeta*bf2f(ev.w));
  *reinterpret_cast<ushort4*>(&xout[base2]) = y;
}

extern "C" void kernel_launch(void* const* d_in, const int* in_sizes, int n_in,
                              void* d_out, int out_size, void* d_ws, size_t ws_size,
                              hipStream_t stream){
  const float* x_in = (const float*)d_in[0];
  const int*   ei   = (const int*)d_in[1];
  const float* W1   = (const float*)d_in[2];
  const float* b1   = (const float*)d_in[3];
  const float* lin  = (const float*)d_in[4];
  const float* att  = (const float*)d_in[5];
  const float* lng  = (const float*)d_in[6];
  const float* lnb  = (const float*)d_in[7];
  const float* W2   = (const float*)d_in[8];
  const float* b2   = (const float*)d_in[9];
  float* out = (float*)d_out;

  const int N = in_sizes[0] / 256;   // 50000
  const int E = in_sizes[1] / 2;     // 800000
  const int* row = ei;
  const int* col = ei + E;

  char* basep = (char*)d_ws;
  size_t off = 0;
  auto alloc = [&](size_t bytes)->char*{
    char* p = basep + off;
    off += (bytes + 255) & ~(size_t)255;
    return p;
  };
  ushort* ego    = (ushort*)alloc((size_t)N*256*2);
  ushort* xbuf   = (ushort*)alloc((size_t)N*256*2);
  ushort* hbuf   = (ushort*)alloc((size_t)N*64*2);
  int*    startp = (int*)   alloc((size_t)(N+1)*4);
  int*    deg    = (int*)   alloc((size_t)N*4);   // also reused as cursor
  int*    rowcsr = (int*)   alloc((size_t)E*4);
  int*    colcsr = (int*)   alloc((size_t)E*4);
  int*    bsum   = (int*)   alloc(256*4);
  int*    boff   = (int*)   alloc(256*4);
  ushort* W1s    = (ushort*)alloc((size_t)256*256*2);
  ushort* linh   = (ushort*)alloc((size_t)2*16384*2);
  ushort* linl   = (ushort*)alloc((size_t)2*16384*2);
  ushort* W2h    = (ushort*)alloc((size_t)16384*2);
  ushort* W2l    = (ushort*)alloc((size_t)16384*2);

  int nbN = (N + 255)/256;   // 196
  int nbT = (N + 63)/64;     // 782 tiles
  int NR  = (N + 7)/8;       // node range per XCD class

  // CSR build (binned hist + fill)
  hipMemsetAsync(deg, 0, (size_t)N*4, stream);
  k_hist_bin<<<1024,256,0,stream>>>(row, deg, E, NR);
  k_scan_block<<<nbN,256,0,stream>>>(deg, startp, bsum, N);
  k_scan_bsum<<<1,256,0,stream>>>(bsum, boff, nbN);
  k_scan_add<<<nbN,256,0,stream>>>(startp, boff, N);
  hipMemsetAsync(deg, 0, (size_t)N*4, stream);     // cursor
  k_fill_bin<<<1024,256,0,stream>>>(row, col, startp, deg, colcsr, E, NR);
  k_rowfill<<<nbN,256,0,stream>>>(startp, rowcsr, N);

  // weight prep
  k_prep_w1<<<256,256,0,stream>>>(W1, W1s);
  k_prep_w64<<<64,256,0,stream>>>(lin,          linh,          linl);
  k_prep_w64<<<64,256,0,stream>>>(lin + 16384,  linh + 16384,  linl + 16384);
  k_prep_w64<<<64,256,0,stream>>>(W2, W2h, W2l);

  // MFMA projection + bias + relu + LN -> ego (bf16)
  k_gemm1_mfma<<<nbT,256,0,stream>>>(x_in, W1s, b1, lng, lnb, ego, N);

  for (int L=0; L<2; ++L){
    const ushort* xsrc = (L == 0) ? ego : xbuf;
    k_hgemm_mfma<<<nbT,256,0,stream>>>(xsrc, linh + (size_t)L*16384,
                                       linl + (size_t)L*16384, hbuf, N);
    k_att_agg<<<(N+3)/4,256,0,stream>>>(hbuf, rowcsr, colcsr, startp,
                                        att + (size_t)L*64*4, ego,
                                        lng + (size_t)(L+1)*256, lnb + (size_t)(L+1)*256,
                                        xbuf, N);
  }
  k_out_mfma<<<nbT,256,0,stream>>>(xbuf, W2h, W2l, b2, out, N);
}